// Round 1
// baseline (352.787 us; speedup 1.0000x reference)
//
#include <hip/hip_runtime.h>
#include <math.h>

// ---------------- Kernel 1: SPP quadrant maxes ----------------
// frames: (2048, 3, 224, 224) fp32. One block per (cimg, quadrant).
// quad[(n*3+c)*4 + qr*2+qc] = max over 112x112 quadrant.
__global__ __launch_bounds__(256) void spp_quad_kernel(const float* __restrict__ frames,
                                                       float* __restrict__ quad) {
    int bid  = blockIdx.x;        // 0..24575
    int q    = bid & 3;
    int cimg = bid >> 2;          // 0..6143
    int qr = q >> 1, qc = q & 1;
    const float* base = frames + (size_t)cimg * 50176 + (size_t)qr * 112 * 224 + qc * 112;
    int tid = threadIdx.x;
    float v = -INFINITY;
    // quadrant = 112 rows x 28 float4
    for (int i = tid; i < 3136; i += 256) {
        int row = i / 28;
        int col = i - row * 28;
        const float4 f = *reinterpret_cast<const float4*>(base + row * 224 + col * 4);
        v = fmaxf(v, fmaxf(fmaxf(f.x, f.y), fmaxf(f.z, f.w)));
    }
    // wave64 butterfly reduce
    for (int m = 32; m >= 1; m >>= 1) v = fmaxf(v, __shfl_xor(v, m, 64));
    __shared__ float s[4];
    int wave = tid >> 6;
    if ((tid & 63) == 0) s[wave] = v;
    __syncthreads();
    if (tid == 0) {
        float r = fmaxf(fmaxf(s[0], s[1]), fmaxf(s[2], s[3]));
        quad[cimg * 4 + q] = r;
    }
}

// ---------------- Kernel 2: pooled/forecast/emb ----------------
// One thread per row n (2048 rows).
__global__ __launch_bounds__(256) void prep_kernel(const float* __restrict__ quad,
                                                   const float* __restrict__ Wf,
                                                   const float* __restrict__ bf,
                                                   const float* __restrict__ We,
                                                   const float* __restrict__ be,
                                                   float* __restrict__ out_pooled,
                                                   float* __restrict__ out_fc,
                                                   float* __restrict__ emb,
                                                   float* __restrict__ femb) {
    int n = blockIdx.x * 256 + threadIdx.x;
    if (n >= 2048) return;
    float p[15];
#pragma unroll
    for (int j = 0; j < 12; j++) p[j] = quad[n * 12 + j];
#pragma unroll
    for (int c = 0; c < 3; c++)
        p[12 + c] = fmaxf(fmaxf(p[c * 4 + 0], p[c * 4 + 1]), fmaxf(p[c * 4 + 2], p[c * 4 + 3]));
#pragma unroll
    for (int j = 0; j < 15; j++) out_pooled[n * 15 + j] = p[j];
    float fc[15];
#pragma unroll
    for (int j = 0; j < 15; j++) {
        float a = bf[j];
#pragma unroll
        for (int k = 0; k < 15; k++) a += p[k] * Wf[j * 15 + k];
        fc[j] = a;
        out_fc[n * 15 + j] = a;
    }
#pragma unroll
    for (int j = 0; j < 8; j++) {
        float a  = be[j];
        float a2 = be[j];
#pragma unroll
        for (int k = 0; k < 15; k++) {
            a  += p[k]  * We[j * 15 + k];
            a2 += fc[k] * We[j * 15 + k];
        }
        emb[n * 8 + j]  = a;
        femb[n * 8 + j] = a2;
    }
}

// ---------------- Kernel 3: double-cell LSTM + heads ----------------
// 64 threads = 16 batches x 4 hidden lanes. Serial over S=128.
__device__ __forceinline__ float fsigmoid(float z) {
    return 1.f / (1.f + __expf(-z));
}
__device__ __forceinline__ float ftanh(float z) {
    z = fminf(fmaxf(z, -20.f), 20.f);
    float e = __expf(2.f * z);
    return (e - 1.f) / (e + 1.f);
}

__global__ __launch_bounds__(64) void lstm_kernel(const float* __restrict__ emb,
                                                  const float* __restrict__ femb,
                                                  const float* __restrict__ Wih,
                                                  const float* __restrict__ Whh,
                                                  const float* __restrict__ bih,
                                                  const float* __restrict__ bhh,
                                                  const float* __restrict__ Wp,
                                                  const float* __restrict__ bp,
                                                  float* __restrict__ prog,
                                                  float* __restrict__ fprog) {
    int tid = threadIdx.x;       // 0..63
    int b = tid >> 2, k = tid & 3;
    // gate rows for this lane: i->k, f->4+k, g->8+k, o->12+k
    float wih[4][8], whh[4][4], bsum[4];
#pragma unroll
    for (int g = 0; g < 4; g++) {
        int row = g * 4 + k;
#pragma unroll
        for (int m = 0; m < 8; m++) wih[g][m] = Wih[row * 8 + m];
#pragma unroll
        for (int m = 0; m < 4; m++) whh[g][m] = Whh[row * 4 + m];
        bsum[g] = bih[row] + bhh[row];
    }
    float wpv[4];
#pragma unroll
    for (int m = 0; m < 4; m++) wpv[m] = Wp[m];
    float bpv = bp[0];

    float h[4] = {0.f, 0.f, 0.f, 0.f};   // replicated h (carry)
    float ck = 0.f;                       // this lane's c (carry)

    for (int s = 0; s < 128; s++) {
        const float* x1 = emb  + (size_t)(b * 128 + s) * 8;
        const float* x2 = femb + (size_t)(b * 128 + s) * 8;

        // ---- cell 1 ----
        float acc[4];
#pragma unroll
        for (int g = 0; g < 4; g++) {
            float a = bsum[g];
#pragma unroll
            for (int m = 0; m < 8; m++) a += x1[m] * wih[g][m];
#pragma unroll
            for (int m = 0; m < 4; m++) a += h[m] * whh[g][m];
            acc[g] = a;
        }
        float c1  = fsigmoid(acc[1]) * ck + fsigmoid(acc[0]) * ftanh(acc[2]);
        float h1k = fsigmoid(acc[3]) * ftanh(c1);
        float h1[4];
#pragma unroll
        for (int m = 0; m < 4; m++) h1[m] = __shfl(h1k, m, 4);
        float z = bpv;
#pragma unroll
        for (int m = 0; m < 4; m++) z += h1[m] * wpv[m];
        if (k == 0) prog[b * 128 + s] = fsigmoid(z);

        // ---- cell 2 (from h1, c1; c2 discarded) ----
#pragma unroll
        for (int g = 0; g < 4; g++) {
            float a = bsum[g];
#pragma unroll
            for (int m = 0; m < 8; m++) a += x2[m] * wih[g][m];
#pragma unroll
            for (int m = 0; m < 4; m++) a += h1[m] * whh[g][m];
            acc[g] = a;
        }
        float c2  = fsigmoid(acc[1]) * c1 + fsigmoid(acc[0]) * ftanh(acc[2]);
        float h2k = fsigmoid(acc[3]) * ftanh(c2);
        float h2[4];
#pragma unroll
        for (int m = 0; m < 4; m++) h2[m] = __shfl(h2k, m, 4);
        float z2 = bpv;
#pragma unroll
        for (int m = 0; m < 4; m++) z2 += h2[m] * wpv[m];
        if (k == 0) fprog[b * 128 + s] = fsigmoid(z2);

        // carry = (h1, c1)
#pragma unroll
        for (int m = 0; m < 4; m++) h[m] = h1[m];
        ck = c1;
    }
}

extern "C" void kernel_launch(void* const* d_in, const int* in_sizes, int n_in,
                              void* d_out, int out_size, void* d_ws, size_t ws_size,
                              hipStream_t stream) {
    const float* frames = (const float*)d_in[0];
    const float* Wf     = (const float*)d_in[1];
    const float* bf     = (const float*)d_in[2];
    const float* We     = (const float*)d_in[3];
    const float* be     = (const float*)d_in[4];
    const float* Wih    = (const float*)d_in[5];
    const float* Whh    = (const float*)d_in[6];
    const float* bih    = (const float*)d_in[7];
    const float* bhh    = (const float*)d_in[8];
    const float* Wp     = (const float*)d_in[9];
    const float* bp     = (const float*)d_in[10];

    float* out = (float*)d_out;
    // out layout: progress (2048) | forecasted_progress (2048) | pooled (30720) | forecasted_pooled (30720)
    float* out_prog   = out;
    float* out_fprog  = out + 2048;
    float* out_pooled = out + 4096;
    float* out_fc     = out + 4096 + 30720;

    float* w    = (float*)d_ws;
    float* quad = w;               // 2048*12 = 24576 floats
    float* emb  = w + 24576;       // 2048*8  = 16384 floats
    float* femb = w + 40960;       // 2048*8  = 16384 floats

    spp_quad_kernel<<<24576, 256, 0, stream>>>(frames, quad);
    prep_kernel<<<8, 256, 0, stream>>>(quad, Wf, bf, We, be, out_pooled, out_fc, emb, femb);
    lstm_kernel<<<1, 64, 0, stream>>>(emb, femb, Wih, Whh, bih, bhh, Wp, bp, out_prog, out_fprog);
}

// Round 2
// 310.707 us; speedup vs baseline: 1.1354x; 1.1354x over previous
//
#include <hip/hip_runtime.h>
#include <math.h>

#define NEGINF (-INFINITY)

// ---------------- Kernel 1: SPP quadrant maxes ----------------
// frames: (2048, 3, 224, 224) fp32. One block per image-channel (6144 blocks).
// Each block reads its full 224x224 plane exactly once (no boundary double-fetch)
// and produces 4 quadrant maxes: quad[cimg*4 + (qr*2+qc)].
__global__ __launch_bounds__(256) void spp_kernel(const float* __restrict__ frames,
                                                  float* __restrict__ quad) {
    int cimg = blockIdx.x;  // 0..6143  (= n*3 + c)
    const float4* __restrict__ base =
        reinterpret_cast<const float4*>(frames) + (size_t)cimg * 12544;  // 224*56 float4
    int tid = threadIdx.x;
    float tl = NEGINF, tr = NEGINF, bl = NEGINF, br = NEGINF;
#pragma unroll 7
    for (int it = 0; it < 49; ++it) {
        int idx = (it << 8) + tid;           // 0..12543
        float4 f = base[idx];
        float m = fmaxf(fmaxf(f.x, f.y), fmaxf(f.z, f.w));
        int row = idx / 56;                  // magic-mul division
        int c4  = idx - row * 56;
        bool top  = row < 112;
        bool left = c4 < 28;                 // float4 never crosses the 28-boundary
        float mt = top ? m : NEGINF;
        float mb = top ? NEGINF : m;
        tl = fmaxf(tl, left ? mt : NEGINF);
        tr = fmaxf(tr, left ? NEGINF : mt);
        bl = fmaxf(bl, left ? mb : NEGINF);
        br = fmaxf(br, left ? NEGINF : mb);
    }
#pragma unroll
    for (int m = 32; m >= 1; m >>= 1) {
        tl = fmaxf(tl, __shfl_xor(tl, m, 64));
        tr = fmaxf(tr, __shfl_xor(tr, m, 64));
        bl = fmaxf(bl, __shfl_xor(bl, m, 64));
        br = fmaxf(br, __shfl_xor(br, m, 64));
    }
    __shared__ float s[4][4];
    int w = tid >> 6;
    if ((tid & 63) == 0) { s[w][0] = tl; s[w][1] = tr; s[w][2] = bl; s[w][3] = br; }
    __syncthreads();
    if (tid < 4) {
        float r = fmaxf(fmaxf(s[0][tid], s[1][tid]), fmaxf(s[2][tid], s[3][tid]));
        quad[cimg * 4 + tid] = r;
    }
}

// ---------------- Kernel 2: fused prep + LSTM ----------------
#define BSTRIDE 1036  // floats per batch in LDS: 128*8 + 12 pad (2-way bank groups, 16B aligned)

template <int M>
__device__ __forceinline__ float qbcast(float v) {
    // DPP quad_perm broadcast of lane M within each 4-lane quad (VALU, no LDS)
    return __int_as_float(
        __builtin_amdgcn_update_dpp(0, __float_as_int(v), M * 0x55, 0xF, 0xF, true));
}

__device__ __forceinline__ float fsigmoid(float z) { return 1.f / (1.f + __expf(-z)); }
__device__ __forceinline__ float ftanh(float z) {
    z = fminf(fmaxf(z, -20.f), 20.f);
    float e = __expf(2.f * z);
    return (e - 1.f) / (e + 1.f);
}

__device__ __forceinline__ float dot8(const float4& a, const float4& b,
                                      const float* __restrict__ w) {
    return a.x * w[0] + a.y * w[1] + a.z * w[2] + a.w * w[3] +
           b.x * w[4] + b.y * w[5] + b.z * w[6] + b.w * w[7];
}

__global__ __launch_bounds__(512, 1) void prep_lstm_kernel(
    const float* __restrict__ quad, const float* __restrict__ Wf,
    const float* __restrict__ bf, const float* __restrict__ We,
    const float* __restrict__ be, const float* __restrict__ Wih,
    const float* __restrict__ Whh, const float* __restrict__ bih,
    const float* __restrict__ bhh, const float* __restrict__ Wp,
    const float* __restrict__ bp, float* __restrict__ out_pooled,
    float* __restrict__ out_fc, float* __restrict__ prog,
    float* __restrict__ fprog) {
    extern __shared__ float lds[];
    float* lemb  = lds;                  // [16][BSTRIDE]
    float* lfemb = lds + 16 * BSTRIDE;   // [16][BSTRIDE]
    int tid = threadIdx.x;

    // ---- Phase 1: pooled / forecast / embeddings (512 threads, 4 rows each) ----
    for (int n = tid; n < 2048; n += 512) {
        float p[15];
        float4 q0 = *(const float4*)(quad + n * 12);
        float4 q1 = *(const float4*)(quad + n * 12 + 4);
        float4 q2 = *(const float4*)(quad + n * 12 + 8);
        p[0] = q0.x; p[1] = q0.y; p[2] = q0.z; p[3] = q0.w;
        p[4] = q1.x; p[5] = q1.y; p[6] = q1.z; p[7] = q1.w;
        p[8] = q2.x; p[9] = q2.y; p[10] = q2.z; p[11] = q2.w;
#pragma unroll
        for (int c = 0; c < 3; c++)
            p[12 + c] = fmaxf(fmaxf(p[c * 4 + 0], p[c * 4 + 1]),
                              fmaxf(p[c * 4 + 2], p[c * 4 + 3]));
#pragma unroll
        for (int j = 0; j < 15; j++) out_pooled[n * 15 + j] = p[j];
        float fc[15];
#pragma unroll
        for (int j = 0; j < 15; j++) {
            float a = bf[j];
#pragma unroll
            for (int kk = 0; kk < 15; kk++) a += p[kk] * Wf[j * 15 + kk];
            fc[j] = a;
            out_fc[n * 15 + j] = a;
        }
        int b = n >> 7, sidx = n & 127;
        float* le = lemb  + b * BSTRIDE + sidx * 8;
        float* lf = lfemb + b * BSTRIDE + sidx * 8;
#pragma unroll
        for (int j = 0; j < 8; j++) {
            float a = be[j], a2 = be[j];
#pragma unroll
            for (int kk = 0; kk < 15; kk++) {
                a  += p[kk]  * We[j * 15 + kk];
                a2 += fc[kk] * We[j * 15 + kk];
            }
            le[j] = a;
            lf[j] = a2;
        }
    }
    __syncthreads();

    // ---- Phase 2: double-cell LSTM, single wave (16 batches x 4 hidden lanes) ----
    if (tid >= 64) return;
    int b = tid >> 2, k = tid & 3;
    float wih[4][8], whh[4][4], bsum[4];
#pragma unroll
    for (int g = 0; g < 4; g++) {
        int row = g * 4 + k;
#pragma unroll
        for (int m = 0; m < 8; m++) wih[g][m] = Wih[row * 8 + m];
#pragma unroll
        for (int m = 0; m < 4; m++) whh[g][m] = Whh[row * 4 + m];
        bsum[g] = bih[row] + bhh[row];
    }
    float wpv[4];
#pragma unroll
    for (int m = 0; m < 4; m++) wpv[m] = Wp[m];
    float bpv = bp[0];

    const float* xe = lemb  + b * BSTRIDE;
    const float* xf = lfemb + b * BSTRIDE;

    // x-dot for step 0 (carry-independent part of the gates)
    float xd1[4], xd2[4];
    {
        float4 a0 = *(const float4*)(xe);
        float4 a1 = *(const float4*)(xe + 4);
        float4 f0 = *(const float4*)(xf);
        float4 f1 = *(const float4*)(xf + 4);
#pragma unroll
        for (int g = 0; g < 4; g++) {
            xd1[g] = bsum[g] + dot8(a0, a1, wih[g]);
            xd2[g] = bsum[g] + dot8(f0, f1, wih[g]);
        }
    }

    float h0 = 0.f, h1r = 0.f, h2r = 0.f, h3r = 0.f;
    float ck = 0.f;

    for (int s2 = 0; s2 < 128; ++s2) {
        // prefetch next step's x (s2=127 reads the pad region: harmless, unused)
        const float* nxe = xe + (s2 + 1) * 8;
        const float* nxf = xf + (s2 + 1) * 8;
        float4 na0 = *(const float4*)(nxe);
        float4 na1 = *(const float4*)(nxe + 4);
        float4 nf0 = *(const float4*)(nxf);
        float4 nf1 = *(const float4*)(nxf + 4);

        // ---- cell 1 ----
        float g0 = xd1[0] + h0 * whh[0][0] + h1r * whh[0][1] + h2r * whh[0][2] + h3r * whh[0][3];
        float g1 = xd1[1] + h0 * whh[1][0] + h1r * whh[1][1] + h2r * whh[1][2] + h3r * whh[1][3];
        float g2 = xd1[2] + h0 * whh[2][0] + h1r * whh[2][1] + h2r * whh[2][2] + h3r * whh[2][3];
        float g3 = xd1[3] + h0 * whh[3][0] + h1r * whh[3][1] + h2r * whh[3][2] + h3r * whh[3][3];
        float c1  = fsigmoid(g1) * ck + fsigmoid(g0) * ftanh(g2);
        float hk1 = fsigmoid(g3) * ftanh(c1);
        float b0 = qbcast<0>(hk1), b1 = qbcast<1>(hk1), b2 = qbcast<2>(hk1), b3 = qbcast<3>(hk1);
        float z = bpv + b0 * wpv[0] + b1 * wpv[1] + b2 * wpv[2] + b3 * wpv[3];
        if (k == 0) prog[b * 128 + s2] = fsigmoid(z);

        // ---- cell 2 (from h1, c1; its c is discarded) ----
        float e0 = xd2[0] + b0 * whh[0][0] + b1 * whh[0][1] + b2 * whh[0][2] + b3 * whh[0][3];
        float e1 = xd2[1] + b0 * whh[1][0] + b1 * whh[1][1] + b2 * whh[1][2] + b3 * whh[1][3];
        float e2 = xd2[2] + b0 * whh[2][0] + b1 * whh[2][1] + b2 * whh[2][2] + b3 * whh[2][3];
        float e3 = xd2[3] + b0 * whh[3][0] + b1 * whh[3][1] + b2 * whh[3][2] + b3 * whh[3][3];
        float c2v = fsigmoid(e1) * c1 + fsigmoid(e0) * ftanh(e2);
        float hk2 = fsigmoid(e3) * ftanh(c2v);
        float d0 = qbcast<0>(hk2), d1 = qbcast<1>(hk2), d2 = qbcast<2>(hk2), d3 = qbcast<3>(hk2);
        float z2 = bpv + d0 * wpv[0] + d1 * wpv[1] + d2 * wpv[2] + d3 * wpv[3];
        if (k == 0) fprog[b * 128 + s2] = fsigmoid(z2);

        // carry = (h1, c1)
        h0 = b0; h1r = b1; h2r = b2; h3r = b3; ck = c1;

        // next step's carry-independent x-dots (off the critical path)
#pragma unroll
        for (int g = 0; g < 4; g++) {
            xd1[g] = bsum[g] + dot8(na0, na1, wih[g]);
            xd2[g] = bsum[g] + dot8(nf0, nf1, wih[g]);
        }
    }
}

extern "C" void kernel_launch(void* const* d_in, const int* in_sizes, int n_in,
                              void* d_out, int out_size, void* d_ws, size_t ws_size,
                              hipStream_t stream) {
    const float* frames = (const float*)d_in[0];
    const float* Wf     = (const float*)d_in[1];
    const float* bf     = (const float*)d_in[2];
    const float* We     = (const float*)d_in[3];
    const float* be     = (const float*)d_in[4];
    const float* Wih    = (const float*)d_in[5];
    const float* Whh    = (const float*)d_in[6];
    const float* bih    = (const float*)d_in[7];
    const float* bhh    = (const float*)d_in[8];
    const float* Wp     = (const float*)d_in[9];
    const float* bp     = (const float*)d_in[10];

    float* out = (float*)d_out;
    float* out_prog   = out;                  // (16,128)
    float* out_fprog  = out + 2048;           // (16,128)
    float* out_pooled = out + 4096;           // (16,128,15)
    float* out_fc     = out + 4096 + 30720;   // (16,128,15)

    float* quad = (float*)d_ws;               // 6144*4 = 24576 floats

    spp_kernel<<<6144, 256, 0, stream>>>(frames, quad);
    size_t lds_bytes = (size_t)2 * 16 * BSTRIDE * sizeof(float);  // 132,608 B
    prep_lstm_kernel<<<1, 512, lds_bytes, stream>>>(quad, Wf, bf, We, be, Wih, Whh,
                                                    bih, bhh, Wp, bp, out_pooled,
                                                    out_fc, out_prog, out_fprog);
}